// Round 18
// baseline (477.012 us; speedup 1.0000x reference)
//
#include <hip/hip_runtime.h>

// DeepCNF: 5x conv1d(K=11)+tanh -> 1x1 conv to 8 tags -> CRF NLL (sum over batch).
// B=128 T=1024 IN=42 HID=256 K=11 NTAGS=8.
// Mid convs: fp8 e4m3, MX-scaled K=128 MFMA (scales=1.0, 2.25x K=32 rate).
// r14/r16/r17 all pinned MfmaUtil at ~34.5% across three register-pipeline
// variants -> per-wave pipelining is not the lever; Occupancy 29% is.
// This round: squeeze to <=128 regs/wave (acc 64 + A 32 + B-2slot 16 + temps)
// -> launch_bounds(256,4): 4 blocks/CU, 16 waves, 4 waves/SIMD. Same r14
// loop shape (single A buffer at iter top, B 2-slot rotation).
// Block = 64t x 256co, 4 waves (wc=co-quarter), 19KB LDS.
// Weights pre-scaled x256 (e4m3 subnormal avoidance), epilogue x1/256.
// H (fp8): row = (b*T+t)*256 bytes, 16B chunks stored at (chunk ^ (t&15)).
// conv4 fuses the emission projection via LDS partial reduce (no atomics).
// CRF: log-semiring segment matrix products (32 segments of 32 steps).

#define B_ 128
#define T_ 1024
#define IN_DIM_ 42
#define HID_ 256
#define KW_ 11
#define NTAGS_ 8
#define SEG_ 32
#define SEGL_ (T_ / SEG_)   // 32

typedef __bf16 bf16x8 __attribute__((ext_vector_type(8)));
typedef float f32x4 __attribute__((ext_vector_type(4)));
typedef short s16x8 __attribute__((ext_vector_type(8)));
typedef int i32x4 __attribute__((ext_vector_type(4)));
typedef int i32x8 __attribute__((ext_vector_type(8)));

struct i4pair { i32x4 lo, hi; };
__device__ __forceinline__ i32x8 mk8(i32x4 lo, i32x4 hi) {
    i4pair p{lo, hi};
    return __builtin_bit_cast(i32x8, p);
}

__device__ __forceinline__ unsigned short f2bf(float f) {
    unsigned u = __builtin_bit_cast(unsigned, f);
    u += 0x7FFFu + ((u >> 16) & 1u);   // RNE
    return (unsigned short)(u >> 16);
}
__device__ __forceinline__ float fast_tanh(float x) {
    float e = __expf(2.f * x);          // inf/0 saturate to +-1 correctly
    return 1.f - 2.f / (e + 1.f);
}
__device__ __forceinline__ unsigned char f2fp8(float v) {
    return (unsigned char)(__builtin_amdgcn_cvt_pk_fp8_f32(v, v, 0, false) & 0xff);
}

#define SZ0_ (KW_ * 2 * 16 * 512)       // layer0 bf16 table (shorts), k-major
#define SZF8_ (22 * 16 * 64 * 32)       // per mid layer fp8 K128 table = 720896 B

// ---------------------------------------------------------------------------
// Pack layer-0 weights fp32 -> bf16 16x16 B-frags, k-major (it2 = k*2+cic):
// wp[((it2*16+coc)*64+lane)*8+e] = w0[coc*16+(l&15)][cic*32+((l>>4)&3)*8+e][k]
// ---------------------------------------------------------------------------
__global__ void pack_l0(const float* __restrict__ w0, unsigned short* __restrict__ wp) {
    for (int idx = blockIdx.x * 256 + threadIdx.x; idx < SZ0_;
         idx += gridDim.x * 256) {
        int it2 = idx >> 13;
        int cic = it2 & 1, k = it2 >> 1;
        int e    = idx & 7;
        int lane = (idx >> 3) & 63;
        int coc  = (idx >> 9) & 15;
        int co = coc * 16 + (lane & 15);
        int ci = cic * 32 + ((lane >> 4) & 3) * 8 + e;
        float v = (ci < IN_DIM_) ? w0[(co * IN_DIM_ + ci) * KW_ + k] : 0.f;
        wp[idx] = f2bf(v);
    }
}

// ---------------------------------------------------------------------------
// Pack mid weights fp32 -> fp8 e4m3 (x256), K=128 B-frags, it = cic128*11+k:
// wp8[((it*16+coc)*64+lane)*32+e] =
//   fp8(256 * w[coc*16+(l&15)][cic128*128+(l>>4)*32+e][k])
// ---------------------------------------------------------------------------
__global__ void pack_f8(const float* __restrict__ w1, const float* __restrict__ w2,
                        const float* __restrict__ w3, const float* __restrict__ w4,
                        unsigned char* __restrict__ wp8) {
    const int total = 4 * SZF8_;
    for (int idx = blockIdx.x * 256 + threadIdx.x; idx < total;
         idx += gridDim.x * 256) {
        int L   = idx / SZF8_;
        int loc = idx - L * SZF8_;
        const float* w = (L == 0) ? w1 : (L == 1) ? w2 : (L == 2) ? w3 : w4;
        int e    = loc & 31;
        int lane = (loc >> 5) & 63;
        int coc  = (loc >> 11) & 15;
        int it   = loc >> 15;          // 0..21
        int cic  = it / KW_;
        int k    = it - cic * KW_;
        int co = coc * 16 + (lane & 15);
        int ci = cic * 128 + (lane >> 4) * 32 + e;
        wp8[idx] = f2fp8(256.f * w[(co * HID_ + ci) * KW_ + k]);
    }
}

// ---------------------------------------------------------------------------
// First conv layer: fp32 x (42ch) input, 128t x 256co block, 8 waves
// (2 t-halves x 4 co-quarters), bf16 16x16x32 MFMA, CIN padded to 64.
// Output: fp8 H (16B-chunk swizzle by t&15).
// ---------------------------------------------------------------------------
__global__ __launch_bounds__(512, 4)
void conv_first(const float* __restrict__ x, const unsigned short* __restrict__ wpack,
                const float* __restrict__ bias, unsigned char* __restrict__ out) {
    constexpr int CIN = 64, ROWS = 138;
    __shared__ unsigned short lds[ROWS * CIN];

    const int tid  = threadIdx.x;
    const int wave = tid >> 6;
    const int lane = tid & 63;
    const int l15  = lane & 15;
    const int lhi  = lane >> 4;
    const int wr   = wave >> 2;
    const int wc   = wave & 3;
    const int b    = blockIdx.x >> 3;
    const int t0   = (blockIdx.x & 7) * 128;

    for (int u = tid; u < ROWS * 32; u += 512) {
        int r = u >> 5, m = u & 31;        // m = float2 index, ci0 = 2m
        int gt = t0 - 5 + r;
        unsigned val = 0;
        if (gt >= 0 && gt < T_ && 2 * m < IN_DIM_) {
            float2 f = *(const float2*)&x[((size_t)b * T_ + gt) * IN_DIM_ + 2 * m];
            val = (unsigned)f2bf(f.x) | ((unsigned)f2bf(f.y) << 16);
        }
        int c = m >> 2;
        int p = c ^ ((r + 3) & 7);
        ((unsigned*)lds)[(r * CIN + p * 8) / 2 + (m & 3)] = val;
    }
    __syncthreads();

    f32x4 acc[4][4];
#pragma unroll
    for (int tf = 0; tf < 4; ++tf)
#pragma unroll
        for (int n = 0; n < 4; ++n) acc[tf][n] = (f32x4){0.f, 0.f, 0.f, 0.f};

    const unsigned short* wpq = wpack + (size_t)(wc * 4) * 512 + lane * 8;
    const int arow = (wr * 64 + l15) * CIN;
    const int l153 = l15 + 3;

    s16x8 Bq[2][4];
#pragma unroll
    for (int n = 0; n < 4; ++n) Bq[0][n] = *(const s16x8*)&wpq[n * 512];

#pragma unroll
    for (int k = 0; k < KW_; ++k) {
#pragma unroll
        for (int cic = 0; cic < 2; ++cic) {
            const int it2 = k * 2 + cic;
            const int nxt = it2 + 1;       // overrun into f8 table: harmless
#pragma unroll
            for (int n = 0; n < 4; ++n)
                Bq[nxt & 1][n] = *(const s16x8*)&wpq[(size_t)nxt * 8192 + n * 512];
            const int key = (l153 + k) & 7;
            const int ao  = arow + (((cic * 4 + lhi) ^ key) << 3);
            s16x8 a0 = *(const s16x8*)&lds[ao + (0 * 16 + k) * CIN];
            s16x8 a1 = *(const s16x8*)&lds[ao + (1 * 16 + k) * CIN];
            s16x8 a2 = *(const s16x8*)&lds[ao + (2 * 16 + k) * CIN];
            s16x8 a3 = *(const s16x8*)&lds[ao + (3 * 16 + k) * CIN];
            __builtin_amdgcn_s_setprio(1);
#pragma unroll
            for (int n = 0; n < 4; ++n) {
                bf16x8 bb = __builtin_bit_cast(bf16x8, Bq[it2 & 1][n]);
                acc[0][n] = __builtin_amdgcn_mfma_f32_16x16x32_bf16(
                    __builtin_bit_cast(bf16x8, a0), bb, acc[0][n], 0, 0, 0);
                acc[1][n] = __builtin_amdgcn_mfma_f32_16x16x32_bf16(
                    __builtin_bit_cast(bf16x8, a1), bb, acc[1][n], 0, 0, 0);
                acc[2][n] = __builtin_amdgcn_mfma_f32_16x16x32_bf16(
                    __builtin_bit_cast(bf16x8, a2), bb, acc[2][n], 0, 0, 0);
                acc[3][n] = __builtin_amdgcn_mfma_f32_16x16x32_bf16(
                    __builtin_bit_cast(bf16x8, a3), bb, acc[3][n], 0, 0, 0);
            }
            __builtin_amdgcn_s_setprio(0);
        }
    }

    // epilogue: bias + tanh -> fp8, stored 16B-chunk-swizzled by (t&15)
#pragma unroll
    for (int n = 0; n < 4; ++n) {
        int co = wc * 64 + n * 16 + l15;
        float bv = bias[co];
        int cch = co >> 4, cby = co & 15;
#pragma unroll
        for (int tf = 0; tf < 4; ++tf) {
#pragma unroll
            for (int r4 = 0; r4 < 4; ++r4) {
                int t = t0 + wr * 64 + tf * 16 + lhi * 4 + r4;
                float v = fast_tanh(acc[tf][n][r4] + bv);
                out[((size_t)b * T_ + t) * 256 + ((cch ^ (t & 15)) << 4) + cby] =
                    f2fp8(v);
            }
        }
    }
}

// ---------------------------------------------------------------------------
// Mid conv (fp8, K=128 scaled MFMA): 64t x 256co block, 4 waves, wave tile
// 64t x 64co, 22 rolled iterations of 16 MFMA. Single A buffer + B 2-slot
// rotation. launch_bounds(256,4): 16 waves/CU, <=128 regs/wave target.
// LAST: fused emission projection via LDS partial reduce (no atomics).
// ---------------------------------------------------------------------------
template <bool LAST>
__global__ __launch_bounds__(256, 4)
void conv_mid(const unsigned char* __restrict__ Hin,
              const unsigned char* __restrict__ wpack,
              const float* __restrict__ bias, unsigned char* __restrict__ out,
              const float* __restrict__ w_out, float* __restrict__ emout) {
    extern __shared__ unsigned char lds8[];   // [76][256] = 19456 B

    const int tid  = threadIdx.x;
    const int wave = tid >> 6;
    const int lane = tid & 63;
    const int l15  = lane & 15;
    const int lhi  = lane >> 4;
    const int wc   = wave;                    // co-quarter
    const int b    = blockIdx.x >> 4;
    const int t0   = (blockIdx.x & 15) * 64;

    // ---- stage rows [t0-5, t0+69) as verbatim 256B rows (swizzle carried) --
    for (int c = wave; c < 19; c += 4) {
        int r0 = c * 4;
        int r  = r0 + (lane >> 4);
        int gt = t0 - 5 + r;
        gt = gt < 0 ? 0 : (gt >= T_ ? T_ - 1 : gt);   // clamp; zeroed below
        const unsigned char* src =
            Hin + ((size_t)b * T_ + gt) * 256 + (lane & 15) * 16;
        __builtin_amdgcn_global_load_lds(
            (const __attribute__((address_space(1))) void*)src,
            (__attribute__((address_space(3))) void*)&lds8[r0 * 256], 16, 0, 0);
    }
    __syncthreads();
    if (t0 == 0) {
        for (int u = tid; u < 320; u += 256)
            ((unsigned*)lds8)[u] = 0;                  // rows 0..4
    }
    if (t0 == T_ - 64) {
        for (int u = tid; u < 320; u += 256)
            ((unsigned*)&lds8[69 * 256])[u] = 0;       // rows 69..73
    }
    __syncthreads();

    f32x4 acc[4][4];
#pragma unroll
    for (int tf = 0; tf < 4; ++tf)
#pragma unroll
        for (int n = 0; n < 4; ++n) acc[tf][n] = (f32x4){0.f, 0.f, 0.f, 0.f};

    const unsigned char* wpB = wpack + (size_t)(wc * 4) * 2048 + lane * 32;

    i32x8 Aa[4], Bs0, Bs1;

    // B frag (itv, nv): 32B at wpB + itv*32768 + nv*2048
#define LOAD_BS(SLOT, itv, nv)                                                 \
    {                                                                          \
        const unsigned char* p_ = wpB + (size_t)(itv) * 32768 + (nv) * 2048;   \
        SLOT = mk8(*(const i32x4*)p_, *(const i32x4*)(p_ + 16));               \
    }
    // one 4-MFMA cluster: column n_ against B slot BS
#define CL(BS, n_)                                                             \
    {                                                                          \
        __builtin_amdgcn_s_setprio(1);                                         \
        _Pragma("unroll") for (int tf = 0; tf < 4; ++tf)                       \
            acc[tf][n_] = __builtin_amdgcn_mfma_scale_f32_16x16x128_f8f6f4(    \
                Aa[tf], BS, acc[tf][n_], 0, 0,                                 \
                0, 0x7F7F7F7F, 0, 0x7F7F7F7F);   /* scales = 1.0 */            \
        __builtin_amdgcn_s_setprio(0);                                         \
    }

    LOAD_BS(Bs0, 0, 0);
    LOAD_BS(Bs1, 0, 1);

    // Rolled runtime K-loop: all register indices static (rule #20 safe).
#pragma unroll 1
    for (int kk = 0; kk < 22; ++kk) {
        // A frag addresses for iteration kk: lane covers
        // ci = cic*128 + lhi*32 + [0,32), row = tf*16 + l15 + k.
        // Chunks c0 = cic*8+lhi*2 and c0+1, stored at (c ^ key),
        // key = (l15+k+11)&15 -> second read is addr ^ 16.
        const int cic_ = kk / KW_;            // uniform: magic-mul, cheap
        const int kn_  = kk - cic_ * KW_;
        const int key_ = (l15 + kn_ + 11) & 15;
        const int ca_  = ((cic_ * 8 + lhi * 2) ^ key_) << 4;
        const int rb_  = (l15 + kn_) * 256 + ca_;
#pragma unroll
        for (int tf = 0; tf < 4; ++tf)
            Aa[tf] = mk8(*(const i32x4*)&lds8[rb_ + tf * 4096],
                         *(const i32x4*)&lds8[(rb_ + tf * 4096) ^ 16]);
        CL(Bs0, 0); LOAD_BS(Bs0, kk, 2);
        CL(Bs1, 1); LOAD_BS(Bs1, kk, 3);
        CL(Bs0, 2); LOAD_BS(Bs0, kk + 1, 0);   // kk=21 -> it 22: overrun
        CL(Bs1, 3); LOAD_BS(Bs1, kk + 1, 1);   // into next table (benign)
    }
#undef LOAD_BS
#undef CL

    constexpr float INV = 1.f / 256.f;   // undo weight scale
    if constexpr (!LAST) {
        // epilogue: bias + tanh -> fp8 H, 16B-chunk swizzle by (t&15)
#pragma unroll
        for (int n = 0; n < 4; ++n) {
            int co = wc * 64 + n * 16 + l15;
            float bv = bias[co];
            int cch = co >> 4, cby = co & 15;
#pragma unroll
            for (int tf = 0; tf < 4; ++tf) {
#pragma unroll
                for (int r4 = 0; r4 < 4; ++r4) {
                    int t = t0 + tf * 16 + lhi * 4 + r4;
                    float v = fast_tanh(acc[tf][n][r4] * INV + bv);
                    out[((size_t)b * T_ + t) * 256 + ((cch ^ (t & 15)) << 4) + cby] =
                        f2fp8(v);
                }
            }
        }
    } else {
        // fused emissions: wave partial over its 64 co -> LDS -> reduce over wc
        float wv[4][NTAGS_], bvn[4];
#pragma unroll
        for (int n = 0; n < 4; ++n) {
            int co = wc * 64 + n * 16 + l15;
            bvn[n] = bias[co];
#pragma unroll
            for (int tg = 0; tg < NTAGS_; ++tg) wv[n][tg] = w_out[tg * HID_ + co];
        }
        __syncthreads();                 // A-tile reads done; reuse LDS
        float* pbuf = (float*)lds8;      // [4 wc][64 t][8 tg] = 8 KB
#pragma unroll
        for (int tf = 0; tf < 4; ++tf) {
#pragma unroll
            for (int r4 = 0; r4 < 4; ++r4) {
                float h[4];
#pragma unroll
                for (int n = 0; n < 4; ++n)
                    h[n] = fast_tanh(acc[tf][n][r4] * INV + bvn[n]);
                float pt[NTAGS_];
#pragma unroll
                for (int tg = 0; tg < NTAGS_; ++tg)
                    pt[tg] = h[0] * wv[0][tg] + h[1] * wv[1][tg] +
                             h[2] * wv[2][tg] + h[3] * wv[3][tg];
#pragma unroll
                for (int off = 8; off; off >>= 1)
#pragma unroll
                    for (int tg = 0; tg < NTAGS_; ++tg)
                        pt[tg] += __shfl_down(pt[tg], off);
                if (l15 == 0) {
                    int tloc = tf * 16 + lhi * 4 + r4;
                    f32x4 lo = {pt[0], pt[1], pt[2], pt[3]};
                    f32x4 hi = {pt[4], pt[5], pt[6], pt[7]};
                    *(f32x4*)&pbuf[(wc * 64 + tloc) * 8]     = lo;
                    *(f32x4*)&pbuf[(wc * 64 + tloc) * 8 + 4] = hi;
                }
            }
        }
        __syncthreads();
        for (int u = tid; u < 64 * NTAGS_; u += 256) {
            float s = pbuf[u] + pbuf[512 + u] + pbuf[1024 + u] + pbuf[1536 + u];
            emout[((size_t)b * T_ + t0) * NTAGS_ + u] = s;
        }
    }
}

// ---------------------------------------------------------------------------
// CRF segment kernel: wave per (b, s). Lane (i=lane>>3, j=lane&7) holds
// M[i][j], lse-product of S_t[i][j] = tr[i][j] + em[b,t,j] + bo[j].
// ---------------------------------------------------------------------------
__global__ __launch_bounds__(256)
void crf_seg_kernel(const float* __restrict__ em, const float* __restrict__ tr,
                    const float* __restrict__ bo, float* __restrict__ segM) {
    const int gw   = blockIdx.x * 4 + (threadIdx.x >> 6);
    const int b    = gw >> 5;
    const int s    = gw & 31;
    const int lane = threadIdx.x & 63;
    const int i    = lane >> 3;
    const int j    = lane & 7;
    const float* emb = em + (size_t)b * T_ * NTAGS_;
    const float boj = bo[j];

    float tc[8];
#pragma unroll
    for (int k = 0; k < 8; ++k) tc[k] = tr[k * 8 + j];

    const int tb = (s == 0) ? 1 : s * SEGL_;
    const int te = (s + 1) * SEGL_;

    float m = tr[i * 8 + j] + emb[tb * 8 + j] + boj;
    for (int t = tb + 1; t < te; ++t) {
        float emt = emb[t * 8 + j] + boj;
        float v[8];
#pragma unroll
        for (int k = 0; k < 8; ++k) v[k] = __shfl(m, (lane & 56) + k) + tc[k];
        float mx = fmaxf(fmaxf(fmaxf(v[0], v[1]), fmaxf(v[2], v[3])),
                         fmaxf(fmaxf(v[4], v[5]), fmaxf(v[6], v[7])));
        float sm = 0.f;
#pragma unroll
        for (int k = 0; k < 8; ++k) sm += __expf(v[k] - mx);
        m = mx + __logf(sm) + emt;
    }
    segM[(size_t)gw * 64 + lane] = m;
}

// ---------------------------------------------------------------------------
// CRF combine: one wave per batch. Numerator + 32-segment fold.
// ---------------------------------------------------------------------------
__global__ __launch_bounds__(64)
void crf_kernel(const float* __restrict__ em, const float* __restrict__ segM,
                const int* __restrict__ tags,
                const float* __restrict__ st, const float* __restrict__ et,
                const float* __restrict__ tr, const float* __restrict__ bo,
                float* __restrict__ outp) {
    __shared__ float sM[SEG_ * 64];
    const int b    = blockIdx.x;
    const int lane = threadIdx.x;
    const float* emb = em + (size_t)b * T_ * NTAGS_;
    const int*   tg  = tags + (size_t)b * T_;

    for (int u = lane; u < SEG_ * 64; u += 64)
        sM[u] = segM[(size_t)b * SEG_ * 64 + u];

    const float breg = bo[lane & 7];

    float num = 0.f;
    for (int t = 1 + lane; t < T_; t += 64) {
        int pt = tg[t - 1], ct = tg[t];
        num += tr[pt * NTAGS_ + ct] + emb[t * NTAGS_ + ct] + __shfl(breg, ct);
    }
#pragma unroll
    for (int off = 32; off; off >>= 1) num += __shfl_down(num, off);
    int tgf = tg[0], tgl = tg[T_ - 1];
    float bo_f = __shfl(breg, tgf);
    float score = 0.f;
    if (lane == 0)
        score = num + st[tgf] + emb[tgf] + bo_f + et[tgl];

    __syncthreads();

    const int j = lane & 7;
    float alpha = st[j] + emb[j] + breg;
    for (int sgm = 0; sgm < SEG_; ++sgm) {
        const float* M = &sM[sgm * 64];
        float v[8];
#pragma unroll
        for (int i = 0; i < 8; ++i) v[i] = __shfl(alpha, i) + M[i * 8 + j];
        float mx = fmaxf(fmaxf(fmaxf(v[0], v[1]), fmaxf(v[2], v[3])),
                         fmaxf(fmaxf(v[4], v[5]), fmaxf(v[6], v[7])));
        float sm = 0.f;
#pragma unroll
        for (int i = 0; i < 8; ++i) sm += __expf(v[i] - mx);
        alpha = mx + __logf(sm);
    }
    float vj = alpha + et[j];
    float w[8];
#pragma unroll
    for (int i = 0; i < 8; ++i) w[i] = __shfl(vj, i);
    float m2 = w[0];
#pragma unroll
    for (int i = 1; i < 8; ++i) m2 = fmaxf(m2, w[i]);
    float s2 = 0.f;
#pragma unroll
    for (int i = 0; i < 8; ++i) s2 += __expf(w[i] - m2);
    float log_z = m2 + __logf(s2);

    if (lane == 0) atomicAdd(outp, log_z - score);
}

// ---------------------------------------------------------------------------
extern "C" void kernel_launch(void* const* d_in, const int* in_sizes, int n_in,
                              void* d_out, int out_size, void* d_ws, size_t ws_size,
                              hipStream_t stream) {
    const float* x     = (const float*)d_in[0];
    const int*   tags  = (const int*)d_in[3];
    const float* w[5]  = {(const float*)d_in[4], (const float*)d_in[6],
                          (const float*)d_in[8], (const float*)d_in[10],
                          (const float*)d_in[12]};
    const float* bias[5] = {(const float*)d_in[5], (const float*)d_in[7],
                            (const float*)d_in[9], (const float*)d_in[11],
                            (const float*)d_in[13]};
    const float* w_out = (const float*)d_in[14];
    const float* b_out = (const float*)d_in[15];
    const float* st    = (const float*)d_in[16];
    const float* et    = (const float*)d_in[17];
    const float* tr    = (const float*)d_in[18];

    // workspace: H0, H1 (fp8), wp0 (bf16), wpf8 x4, em, segM
    unsigned char* H0 = (unsigned char*)d_ws;
    unsigned char* H1 = H0 + (size_t)B_ * T_ * 256;
    unsigned short* wp0 = (unsigned short*)(H1 + (size_t)B_ * T_ * 256);
    unsigned char* wpf8 = (unsigned char*)(wp0 + SZ0_);
    float* em   = (float*)(wpf8 + 4 * (size_t)SZF8_);
    float* segM = em + (size_t)B_ * T_ * NTAGS_;
    // B-prefetch overruns a table by <=1 it-group (32KB): wp0 -> wpf8, wpf8
    // layers into each other, last layer into em (reads only, never consumed).

    pack_l0<<<176, 256, 0, stream>>>(w[0], wp0);
    pack_f8<<<2048, 256, 0, stream>>>(w[1], w[2], w[3], w[4], wpf8);

    conv_first<<<B_ * (T_ / 128), 512, 0, stream>>>(x, wp0, bias[0], H0);

    const int NBLK = B_ * (T_ / 64);   // 2048
    const int MLDS = 76 * 256;         // 19456 B
    unsigned char* wpl[4] = {wpf8, wpf8 + SZF8_, wpf8 + 2 * (size_t)SZF8_,
                             wpf8 + 3 * (size_t)SZF8_};
    conv_mid<false><<<NBLK, 256, MLDS, stream>>>(H0, wpl[0], bias[1], H1,
                                                 nullptr, nullptr);
    conv_mid<false><<<NBLK, 256, MLDS, stream>>>(H1, wpl[1], bias[2], H0,
                                                 nullptr, nullptr);
    conv_mid<false><<<NBLK, 256, MLDS, stream>>>(H0, wpl[2], bias[3], H1,
                                                 nullptr, nullptr);
    conv_mid<true><<<NBLK, 256, MLDS, stream>>>(H1, wpl[3], bias[4], nullptr,
                                                w_out, em);

    crf_seg_kernel<<<B_ * SEG_ / 4, 256, 0, stream>>>(em, tr, b_out, segM);

    hipMemsetAsync(d_out, 0, sizeof(float), stream);
    crf_kernel<<<B_, 64, 0, stream>>>(em, segM, tags, st, et, tr, b_out,
                                      (float*)d_out);
}

// Round 19
// 453.819 us; speedup vs baseline: 1.0511x; 1.0511x over previous
//
#include <hip/hip_runtime.h>

// DeepCNF: 5x conv1d(K=11)+tanh -> 1x1 conv to 8 tags -> CRF NLL (sum over batch).
// B=128 T=1024 IN=42 HID=256 K=11 NTAGS=8.
// Mid convs: fp8 e4m3, MX-scaled K=128 MFMA (scales=1.0, 2.25x K=32 rate).
// r14-r18 invariant (MfmaUtil ~35% across pipeline + occupancy variants)
// diagnosed as B-stream arithmetic-intensity: every 64t block streamed the
// whole 720KB table (A:B traffic 1:37, 1.44GB/layer through L1/L2 ~= the
// MFMA ideal itself). This round: wave tile 128t x 64co (block 128t x 256co)
// -> B bytes per output HALVED, each B load covered by 2x MFMA (32/iter).
// acc 128 + A 64 + B-2slot 16 regs -> launch_bounds(256,2), 35KB LDS,
// 2 blocks/CU. Same rolled-static K-loop (rule #20 safe).
// Weights pre-scaled x256 (e4m3 subnormal avoidance), epilogue x1/256.
// H (fp8): row = (b*T+t)*256 bytes, 16B chunks stored at (chunk ^ (t&15)).
// conv4 fuses the emission projection via LDS partial reduce (no atomics).
// CRF: log-semiring segment matrix products (32 segments of 32 steps).

#define B_ 128
#define T_ 1024
#define IN_DIM_ 42
#define HID_ 256
#define KW_ 11
#define NTAGS_ 8
#define SEG_ 32
#define SEGL_ (T_ / SEG_)   // 32

typedef __bf16 bf16x8 __attribute__((ext_vector_type(8)));
typedef float f32x4 __attribute__((ext_vector_type(4)));
typedef short s16x8 __attribute__((ext_vector_type(8)));
typedef int i32x4 __attribute__((ext_vector_type(4)));
typedef int i32x8 __attribute__((ext_vector_type(8)));

struct i4pair { i32x4 lo, hi; };
__device__ __forceinline__ i32x8 mk8(i32x4 lo, i32x4 hi) {
    i4pair p{lo, hi};
    return __builtin_bit_cast(i32x8, p);
}

__device__ __forceinline__ unsigned short f2bf(float f) {
    unsigned u = __builtin_bit_cast(unsigned, f);
    u += 0x7FFFu + ((u >> 16) & 1u);   // RNE
    return (unsigned short)(u >> 16);
}
__device__ __forceinline__ float fast_tanh(float x) {
    float e = __expf(2.f * x);          // inf/0 saturate to +-1 correctly
    return 1.f - 2.f / (e + 1.f);
}
__device__ __forceinline__ unsigned char f2fp8(float v) {
    return (unsigned char)(__builtin_amdgcn_cvt_pk_fp8_f32(v, v, 0, false) & 0xff);
}

#define SZ0_ (KW_ * 2 * 16 * 512)       // layer0 bf16 table (shorts), k-major
#define SZF8_ (22 * 16 * 64 * 32)       // per mid layer fp8 K128 table = 720896 B

// ---------------------------------------------------------------------------
// Pack layer-0 weights fp32 -> bf16 16x16 B-frags, k-major (it2 = k*2+cic).
// ---------------------------------------------------------------------------
__global__ void pack_l0(const float* __restrict__ w0, unsigned short* __restrict__ wp) {
    for (int idx = blockIdx.x * 256 + threadIdx.x; idx < SZ0_;
         idx += gridDim.x * 256) {
        int it2 = idx >> 13;
        int cic = it2 & 1, k = it2 >> 1;
        int e    = idx & 7;
        int lane = (idx >> 3) & 63;
        int coc  = (idx >> 9) & 15;
        int co = coc * 16 + (lane & 15);
        int ci = cic * 32 + ((lane >> 4) & 3) * 8 + e;
        float v = (ci < IN_DIM_) ? w0[(co * IN_DIM_ + ci) * KW_ + k] : 0.f;
        wp[idx] = f2bf(v);
    }
}

// ---------------------------------------------------------------------------
// Pack mid weights fp32 -> fp8 e4m3 (x256), K=128 B-frags, it = cic128*11+k:
// wp8[((it*16+coc)*64+lane)*32+e] =
//   fp8(256 * w[coc*16+(l&15)][cic128*128+(l>>4)*32+e][k])
// ---------------------------------------------------------------------------
__global__ void pack_f8(const float* __restrict__ w1, const float* __restrict__ w2,
                        const float* __restrict__ w3, const float* __restrict__ w4,
                        unsigned char* __restrict__ wp8) {
    const int total = 4 * SZF8_;
    for (int idx = blockIdx.x * 256 + threadIdx.x; idx < total;
         idx += gridDim.x * 256) {
        int L   = idx / SZF8_;
        int loc = idx - L * SZF8_;
        const float* w = (L == 0) ? w1 : (L == 1) ? w2 : (L == 2) ? w3 : w4;
        int e    = loc & 31;
        int lane = (loc >> 5) & 63;
        int coc  = (loc >> 11) & 15;
        int it   = loc >> 15;          // 0..21
        int cic  = it / KW_;
        int k    = it - cic * KW_;
        int co = coc * 16 + (lane & 15);
        int ci = cic * 128 + (lane >> 4) * 32 + e;
        wp8[idx] = f2fp8(256.f * w[(co * HID_ + ci) * KW_ + k]);
    }
}

// ---------------------------------------------------------------------------
// First conv layer: fp32 x (42ch) input, 128t x 256co block, 8 waves
// (2 t-halves x 4 co-quarters), bf16 16x16x32 MFMA, CIN padded to 64.
// Output: fp8 H (16B-chunk swizzle by t&15).
// ---------------------------------------------------------------------------
__global__ __launch_bounds__(512, 4)
void conv_first(const float* __restrict__ x, const unsigned short* __restrict__ wpack,
                const float* __restrict__ bias, unsigned char* __restrict__ out) {
    constexpr int CIN = 64, ROWS = 138;
    __shared__ unsigned short lds[ROWS * CIN];

    const int tid  = threadIdx.x;
    const int wave = tid >> 6;
    const int lane = tid & 63;
    const int l15  = lane & 15;
    const int lhi  = lane >> 4;
    const int wr   = wave >> 2;
    const int wc   = wave & 3;
    const int b    = blockIdx.x >> 3;
    const int t0   = (blockIdx.x & 7) * 128;

    for (int u = tid; u < ROWS * 32; u += 512) {
        int r = u >> 5, m = u & 31;        // m = float2 index, ci0 = 2m
        int gt = t0 - 5 + r;
        unsigned val = 0;
        if (gt >= 0 && gt < T_ && 2 * m < IN_DIM_) {
            float2 f = *(const float2*)&x[((size_t)b * T_ + gt) * IN_DIM_ + 2 * m];
            val = (unsigned)f2bf(f.x) | ((unsigned)f2bf(f.y) << 16);
        }
        int c = m >> 2;
        int p = c ^ ((r + 3) & 7);
        ((unsigned*)lds)[(r * CIN + p * 8) / 2 + (m & 3)] = val;
    }
    __syncthreads();

    f32x4 acc[4][4];
#pragma unroll
    for (int tf = 0; tf < 4; ++tf)
#pragma unroll
        for (int n = 0; n < 4; ++n) acc[tf][n] = (f32x4){0.f, 0.f, 0.f, 0.f};

    const unsigned short* wpq = wpack + (size_t)(wc * 4) * 512 + lane * 8;
    const int arow = (wr * 64 + l15) * CIN;
    const int l153 = l15 + 3;

    s16x8 Bq[2][4];
#pragma unroll
    for (int n = 0; n < 4; ++n) Bq[0][n] = *(const s16x8*)&wpq[n * 512];

#pragma unroll
    for (int k = 0; k < KW_; ++k) {
#pragma unroll
        for (int cic = 0; cic < 2; ++cic) {
            const int it2 = k * 2 + cic;
            const int nxt = it2 + 1;       // overrun into f8 table: harmless
#pragma unroll
            for (int n = 0; n < 4; ++n)
                Bq[nxt & 1][n] = *(const s16x8*)&wpq[(size_t)nxt * 8192 + n * 512];
            const int key = (l153 + k) & 7;
            const int ao  = arow + (((cic * 4 + lhi) ^ key) << 3);
            s16x8 a0 = *(const s16x8*)&lds[ao + (0 * 16 + k) * CIN];
            s16x8 a1 = *(const s16x8*)&lds[ao + (1 * 16 + k) * CIN];
            s16x8 a2 = *(const s16x8*)&lds[ao + (2 * 16 + k) * CIN];
            s16x8 a3 = *(const s16x8*)&lds[ao + (3 * 16 + k) * CIN];
            __builtin_amdgcn_s_setprio(1);
#pragma unroll
            for (int n = 0; n < 4; ++n) {
                bf16x8 bb = __builtin_bit_cast(bf16x8, Bq[it2 & 1][n]);
                acc[0][n] = __builtin_amdgcn_mfma_f32_16x16x32_bf16(
                    __builtin_bit_cast(bf16x8, a0), bb, acc[0][n], 0, 0, 0);
                acc[1][n] = __builtin_amdgcn_mfma_f32_16x16x32_bf16(
                    __builtin_bit_cast(bf16x8, a1), bb, acc[1][n], 0, 0, 0);
                acc[2][n] = __builtin_amdgcn_mfma_f32_16x16x32_bf16(
                    __builtin_bit_cast(bf16x8, a2), bb, acc[2][n], 0, 0, 0);
                acc[3][n] = __builtin_amdgcn_mfma_f32_16x16x32_bf16(
                    __builtin_bit_cast(bf16x8, a3), bb, acc[3][n], 0, 0, 0);
            }
            __builtin_amdgcn_s_setprio(0);
        }
    }

    // epilogue: bias + tanh -> fp8, stored 16B-chunk-swizzled by (t&15)
#pragma unroll
    for (int n = 0; n < 4; ++n) {
        int co = wc * 64 + n * 16 + l15;
        float bv = bias[co];
        int cch = co >> 4, cby = co & 15;
#pragma unroll
        for (int tf = 0; tf < 4; ++tf) {
#pragma unroll
            for (int r4 = 0; r4 < 4; ++r4) {
                int t = t0 + wr * 64 + tf * 16 + lhi * 4 + r4;
                float v = fast_tanh(acc[tf][n][r4] + bv);
                out[((size_t)b * T_ + t) * 256 + ((cch ^ (t & 15)) << 4) + cby] =
                    f2fp8(v);
            }
        }
    }
}

// ---------------------------------------------------------------------------
// Mid conv (fp8, K=128 scaled MFMA): 128t x 256co block, 4 waves, wave tile
// 128t x 64co (acc[8][4]), 22 rolled iterations of 32 MFMA. Single A buffer
// (16x ds_read_b128) + B 2-slot rotation. launch_bounds(256,2), 35KB LDS,
// 2 blocks/CU. All register indices static (rule #20 safe).
// LAST: fused emission projection via LDS partial reduce (no atomics).
// ---------------------------------------------------------------------------
template <bool LAST>
__global__ __launch_bounds__(256, 2)
void conv_mid(const unsigned char* __restrict__ Hin,
              const unsigned char* __restrict__ wpack,
              const float* __restrict__ bias, unsigned char* __restrict__ out,
              const float* __restrict__ w_out, float* __restrict__ emout) {
    extern __shared__ unsigned char lds8[];   // [140][256] = 35840 B (138 used)

    const int tid  = threadIdx.x;
    const int wave = tid >> 6;
    const int lane = tid & 63;
    const int l15  = lane & 15;
    const int lhi  = lane >> 4;
    const int wc   = wave;                    // co-quarter
    const int b    = blockIdx.x >> 3;
    const int t0   = (blockIdx.x & 7) * 128;

    // ---- stage rows [t0-5, t0+133) as verbatim 256B rows (swizzle carried) --
    for (int c = wave; c < 35; c += 4) {
        int r0 = c * 4;
        int r  = r0 + (lane >> 4);
        int gt = t0 - 5 + r;
        gt = gt < 0 ? 0 : (gt >= T_ ? T_ - 1 : gt);   // clamp; zeroed below
        const unsigned char* src =
            Hin + ((size_t)b * T_ + gt) * 256 + (lane & 15) * 16;
        __builtin_amdgcn_global_load_lds(
            (const __attribute__((address_space(1))) void*)src,
            (__attribute__((address_space(3))) void*)&lds8[r0 * 256], 16, 0, 0);
    }
    __syncthreads();
    if (t0 == 0) {
        for (int u = tid; u < 320; u += 256)
            ((unsigned*)lds8)[u] = 0;                  // rows 0..4
    }
    if (t0 == T_ - 128) {
        for (int u = tid; u < 320; u += 256)
            ((unsigned*)&lds8[133 * 256])[u] = 0;      // rows 133..137
    }
    __syncthreads();

    f32x4 acc[8][4];
#pragma unroll
    for (int tf = 0; tf < 8; ++tf)
#pragma unroll
        for (int n = 0; n < 4; ++n) acc[tf][n] = (f32x4){0.f, 0.f, 0.f, 0.f};

    const unsigned char* wpB = wpack + (size_t)(wc * 4) * 2048 + lane * 32;

    i32x8 Aa[8], Bs0, Bs1;

    // B frag (itv, nv): 32B at wpB + itv*32768 + nv*2048
#define LOAD_BS(SLOT, itv, nv)                                                 \
    {                                                                          \
        const unsigned char* p_ = wpB + (size_t)(itv) * 32768 + (nv) * 2048;   \
        SLOT = mk8(*(const i32x4*)p_, *(const i32x4*)(p_ + 16));               \
    }
    // one 8-MFMA cluster: column n_ against B slot BS
#define CL(BS, n_)                                                             \
    {                                                                          \
        __builtin_amdgcn_s_setprio(1);                                         \
        _Pragma("unroll") for (int tf = 0; tf < 8; ++tf)                       \
            acc[tf][n_] = __builtin_amdgcn_mfma_scale_f32_16x16x128_f8f6f4(    \
                Aa[tf], BS, acc[tf][n_], 0, 0,                                 \
                0, 0x7F7F7F7F, 0, 0x7F7F7F7F);   /* scales = 1.0 */            \
        __builtin_amdgcn_s_setprio(0);                                         \
    }

    LOAD_BS(Bs0, 0, 0);
    LOAD_BS(Bs1, 0, 1);

    // Rolled runtime K-loop: all register indices static (rule #20 safe).
#pragma unroll 1
    for (int kk = 0; kk < 22; ++kk) {
        // A frag addresses for iteration kk: lane covers
        // ci = cic*128 + lhi*32 + [0,32), row = tf*16 + l15 + k (tf 0..7).
        // Chunks c0 = cic*8+lhi*2 and c0+1, stored at (c ^ key),
        // key = (l15+k+11)&15 -> second read is addr ^ 16.
        const int cic_ = kk / KW_;            // uniform: magic-mul, cheap
        const int kn_  = kk - cic_ * KW_;
        const int key_ = (l15 + kn_ + 11) & 15;
        const int ca_  = ((cic_ * 8 + lhi * 2) ^ key_) << 4;
        const int rb_  = (l15 + kn_) * 256 + ca_;
#pragma unroll
        for (int tf = 0; tf < 8; ++tf)
            Aa[tf] = mk8(*(const i32x4*)&lds8[rb_ + tf * 4096],
                         *(const i32x4*)&lds8[(rb_ + tf * 4096) ^ 16]);
        CL(Bs0, 0); LOAD_BS(Bs0, kk, 2);
        CL(Bs1, 1); LOAD_BS(Bs1, kk, 3);
        CL(Bs0, 2); LOAD_BS(Bs0, kk + 1, 0);   // kk=21 -> it 22: overrun
        CL(Bs1, 3); LOAD_BS(Bs1, kk + 1, 1);   // into next table (benign)
    }
#undef LOAD_BS
#undef CL

    constexpr float INV = 1.f / 256.f;   // undo weight scale
    if constexpr (!LAST) {
        // epilogue: bias + tanh -> fp8 H, 16B-chunk swizzle by (t&15)
#pragma unroll
        for (int n = 0; n < 4; ++n) {
            int co = wc * 64 + n * 16 + l15;
            float bv = bias[co];
            int cch = co >> 4, cby = co & 15;
#pragma unroll
            for (int tf = 0; tf < 8; ++tf) {
#pragma unroll
                for (int r4 = 0; r4 < 4; ++r4) {
                    int t = t0 + tf * 16 + lhi * 4 + r4;
                    float v = fast_tanh(acc[tf][n][r4] * INV + bv);
                    out[((size_t)b * T_ + t) * 256 + ((cch ^ (t & 15)) << 4) + cby] =
                        f2fp8(v);
                }
            }
        }
    } else {
        // fused emissions: wave partial over its 64 co -> LDS -> reduce over wc
        float wv[4][NTAGS_], bvn[4];
#pragma unroll
        for (int n = 0; n < 4; ++n) {
            int co = wc * 64 + n * 16 + l15;
            bvn[n] = bias[co];
#pragma unroll
            for (int tg = 0; tg < NTAGS_; ++tg) wv[n][tg] = w_out[tg * HID_ + co];
        }
        __syncthreads();                 // A-tile reads done; reuse LDS
        float* pbuf = (float*)lds8;      // [4 wc][128 t][8 tg] = 16 KB
#pragma unroll
        for (int tf = 0; tf < 8; ++tf) {
#pragma unroll
            for (int r4 = 0; r4 < 4; ++r4) {
                float h[4];
#pragma unroll
                for (int n = 0; n < 4; ++n)
                    h[n] = fast_tanh(acc[tf][n][r4] * INV + bvn[n]);
                float pt[NTAGS_];
#pragma unroll
                for (int tg = 0; tg < NTAGS_; ++tg)
                    pt[tg] = h[0] * wv[0][tg] + h[1] * wv[1][tg] +
                             h[2] * wv[2][tg] + h[3] * wv[3][tg];
#pragma unroll
                for (int off = 8; off; off >>= 1)
#pragma unroll
                    for (int tg = 0; tg < NTAGS_; ++tg)
                        pt[tg] += __shfl_down(pt[tg], off);
                if (l15 == 0) {
                    int tloc = tf * 16 + lhi * 4 + r4;
                    f32x4 lo = {pt[0], pt[1], pt[2], pt[3]};
                    f32x4 hi = {pt[4], pt[5], pt[6], pt[7]};
                    *(f32x4*)&pbuf[(wc * 128 + tloc) * 8]     = lo;
                    *(f32x4*)&pbuf[(wc * 128 + tloc) * 8 + 4] = hi;
                }
            }
        }
        __syncthreads();
        for (int u = tid; u < 128 * NTAGS_; u += 256) {
            float s = pbuf[u] + pbuf[1024 + u] + pbuf[2048 + u] + pbuf[3072 + u];
            emout[((size_t)b * T_ + t0) * NTAGS_ + u] = s;
        }
    }
}

// ---------------------------------------------------------------------------
// CRF segment kernel: wave per (b, s). Lane (i=lane>>3, j=lane&7) holds
// M[i][j], lse-product of S_t[i][j] = tr[i][j] + em[b,t,j] + bo[j].
// ---------------------------------------------------------------------------
__global__ __launch_bounds__(256)
void crf_seg_kernel(const float* __restrict__ em, const float* __restrict__ tr,
                    const float* __restrict__ bo, float* __restrict__ segM) {
    const int gw   = blockIdx.x * 4 + (threadIdx.x >> 6);
    const int b    = gw >> 5;
    const int s    = gw & 31;
    const int lane = threadIdx.x & 63;
    const int i    = lane >> 3;
    const int j    = lane & 7;
    const float* emb = em + (size_t)b * T_ * NTAGS_;
    const float boj = bo[j];

    float tc[8];
#pragma unroll
    for (int k = 0; k < 8; ++k) tc[k] = tr[k * 8 + j];

    const int tb = (s == 0) ? 1 : s * SEGL_;
    const int te = (s + 1) * SEGL_;

    float m = tr[i * 8 + j] + emb[tb * 8 + j] + boj;
    for (int t = tb + 1; t < te; ++t) {
        float emt = emb[t * 8 + j] + boj;
        float v[8];
#pragma unroll
        for (int k = 0; k < 8; ++k) v[k] = __shfl(m, (lane & 56) + k) + tc[k];
        float mx = fmaxf(fmaxf(fmaxf(v[0], v[1]), fmaxf(v[2], v[3])),
                         fmaxf(fmaxf(v[4], v[5]), fmaxf(v[6], v[7])));
        float sm = 0.f;
#pragma unroll
        for (int k = 0; k < 8; ++k) sm += __expf(v[k] - mx);
        m = mx + __logf(sm) + emt;
    }
    segM[(size_t)gw * 64 + lane] = m;
}

// ---------------------------------------------------------------------------
// CRF combine: one wave per batch. Numerator + 32-segment fold.
// ---------------------------------------------------------------------------
__global__ __launch_bounds__(64)
void crf_kernel(const float* __restrict__ em, const float* __restrict__ segM,
                const int* __restrict__ tags,
                const float* __restrict__ st, const float* __restrict__ et,
                const float* __restrict__ tr, const float* __restrict__ bo,
                float* __restrict__ outp) {
    __shared__ float sM[SEG_ * 64];
    const int b    = blockIdx.x;
    const int lane = threadIdx.x;
    const float* emb = em + (size_t)b * T_ * NTAGS_;
    const int*   tg  = tags + (size_t)b * T_;

    for (int u = lane; u < SEG_ * 64; u += 64)
        sM[u] = segM[(size_t)b * SEG_ * 64 + u];

    const float breg = bo[lane & 7];

    float num = 0.f;
    for (int t = 1 + lane; t < T_; t += 64) {
        int pt = tg[t - 1], ct = tg[t];
        num += tr[pt * NTAGS_ + ct] + emb[t * NTAGS_ + ct] + __shfl(breg, ct);
    }
#pragma unroll
    for (int off = 32; off; off >>= 1) num += __shfl_down(num, off);
    int tgf = tg[0], tgl = tg[T_ - 1];
    float bo_f = __shfl(breg, tgf);
    float score = 0.f;
    if (lane == 0)
        score = num + st[tgf] + emb[tgf] + bo_f + et[tgl];

    __syncthreads();

    const int j = lane & 7;
    float alpha = st[j] + emb[j] + breg;
    for (int sgm = 0; sgm < SEG_; ++sgm) {
        const float* M = &sM[sgm * 64];
        float v[8];
#pragma unroll
        for (int i = 0; i < 8; ++i) v[i] = __shfl(alpha, i) + M[i * 8 + j];
        float mx = fmaxf(fmaxf(fmaxf(v[0], v[1]), fmaxf(v[2], v[3])),
                         fmaxf(fmaxf(v[4], v[5]), fmaxf(v[6], v[7])));
        float sm = 0.f;
#pragma unroll
        for (int i = 0; i < 8; ++i) sm += __expf(v[i] - mx);
        alpha = mx + __logf(sm);
    }
    float vj = alpha + et[j];
    float w[8];
#pragma unroll
    for (int i = 0; i < 8; ++i) w[i] = __shfl(vj, i);
    float m2 = w[0];
#pragma unroll
    for (int i = 1; i < 8; ++i) m2 = fmaxf(m2, w[i]);
    float s2 = 0.f;
#pragma unroll
    for (int i = 0; i < 8; ++i) s2 += __expf(w[i] - m2);
    float log_z = m2 + __logf(s2);

    if (lane == 0) atomicAdd(outp, log_z - score);
}

// ---------------------------------------------------------------------------
extern "C" void kernel_launch(void* const* d_in, const int* in_sizes, int n_in,
                              void* d_out, int out_size, void* d_ws, size_t ws_size,
                              hipStream_t stream) {
    const float* x     = (const float*)d_in[0];
    const int*   tags  = (const int*)d_in[3];
    const float* w[5]  = {(const float*)d_in[4], (const float*)d_in[6],
                          (const float*)d_in[8], (const float*)d_in[10],
                          (const float*)d_in[12]};
    const float* bias[5] = {(const float*)d_in[5], (const float*)d_in[7],
                            (const float*)d_in[9], (const float*)d_in[11],
                            (const float*)d_in[13]};
    const float* w_out = (const float*)d_in[14];
    const float* b_out = (const float*)d_in[15];
    const float* st    = (const float*)d_in[16];
    const float* et    = (const float*)d_in[17];
    const float* tr    = (const float*)d_in[18];

    // workspace: H0, H1 (fp8), wp0 (bf16), wpf8 x4, em, segM
    unsigned char* H0 = (unsigned char*)d_ws;
    unsigned char* H1 = H0 + (size_t)B_ * T_ * 256;
    unsigned short* wp0 = (unsigned short*)(H1 + (size_t)B_ * T_ * 256);
    unsigned char* wpf8 = (unsigned char*)(wp0 + SZ0_);
    float* em   = (float*)(wpf8 + 4 * (size_t)SZF8_);
    float* segM = em + (size_t)B_ * T_ * NTAGS_;
    // B-prefetch overruns a table by <=1 it-group (32KB): wp0 -> wpf8, wpf8
    // layers into each other, last layer into em (reads only, never consumed).

    pack_l0<<<176, 256, 0, stream>>>(w[0], wp0);
    pack_f8<<<2048, 256, 0, stream>>>(w[1], w[2], w[3], w[4], wpf8);

    conv_first<<<B_ * (T_ / 128), 512, 0, stream>>>(x, wp0, bias[0], H0);

    const int NBLK = B_ * (T_ / 128);  // 1024
    const int MLDS = 140 * 256;        // 35840 B
    unsigned char* wpl[4] = {wpf8, wpf8 + SZF8_, wpf8 + 2 * (size_t)SZF8_,
                             wpf8 + 3 * (size_t)SZF8_};
    conv_mid<false><<<NBLK, 256, MLDS, stream>>>(H0, wpl[0], bias[1], H1,
                                                 nullptr, nullptr);
    conv_mid<false><<<NBLK, 256, MLDS, stream>>>(H1, wpl[1], bias[2], H0,
                                                 nullptr, nullptr);
    conv_mid<false><<<NBLK, 256, MLDS, stream>>>(H0, wpl[2], bias[3], H1,
                                                 nullptr, nullptr);
    conv_mid<true><<<NBLK, 256, MLDS, stream>>>(H1, wpl[3], bias[4], nullptr,
                                                w_out, em);

    crf_seg_kernel<<<B_ * SEG_ / 4, 256, 0, stream>>>(em, tr, b_out, segM);

    hipMemsetAsync(d_out, 0, sizeof(float), stream);
    crf_kernel<<<B_, 64, 0, stream>>>(em, segM, tags, st, et, tr, b_out,
                                      (float*)d_out);
}